// Round 8
// baseline (962.630 us; speedup 1.0000x reference)
//
#include <hip/hip_runtime.h>

typedef unsigned short ushort_t;
typedef unsigned int uint_t;
typedef __attribute__((ext_vector_type(8))) short short8;
typedef __attribute__((ext_vector_type(4))) float f32x4;

static constexpr int V = 32000, H = 512, HALFD = 256, LSEQ = 1024, BB = 64;

__device__ __forceinline__ ushort_t f2bf(float f) {
    uint_t u = __float_as_uint(f);
    u = (u + 0x7FFFu + ((u >> 16) & 1u)) >> 16;
    return (ushort_t)u;
}
__device__ __forceinline__ float bf2f(ushort_t u) {
    return __uint_as_float(((uint_t)u) << 16);
}
__device__ __forceinline__ float bflo(uint_t u) { return __uint_as_float(u << 16); }
__device__ __forceinline__ float bfhi(uint_t u) { return __uint_as_float(u & 0xffff0000u); }

// ---------------- weight transpose + fp32->bf16 convert: Wt[n][k] = bf16(W[k][n]) --
__global__ void transpose_cvt(const float* __restrict__ W, ushort_t* __restrict__ Wt,
                              int K, int N) {
    __shared__ float tile[32][33];
    int k0 = blockIdx.y * 32, n0 = blockIdx.x * 32;
    int tx = threadIdx.x & 31, ty = threadIdx.x >> 5;   // 256 threads: ty 0..7
    #pragma unroll
    for (int i = 0; i < 32; i += 8)
        tile[ty + i][tx] = W[(size_t)(k0 + ty + i) * N + n0 + tx];
    __syncthreads();
    #pragma unroll
    for (int i = 0; i < 32; i += 8)
        Wt[(size_t)(n0 + ty + i) * K + k0 + tx] = f2bf(tile[tx][ty + i]);
}

// ================= fully fused encoder ============================================
// One dispatch replaces 8x(ffn1+ffn2+ln+proj) + 2 beta (34 dispatches).
// Block = 64 rows, 512 threads (8 waves). Intermediates (t1, x, h) never leave
// the block: e in LDS bf16; 4 slices of hidden-1024 {GEMM1 -> relu -> t1 LDS ->
// GEMM2 partial into x regs}; +b2 + fp32 residual; cross-wave LayerNorm; h in LDS;
// proj GEMM (semt|epit concat rows); beta fused in epilogue.
// r7 post-mortem: 3 encoder micro-structures all ~370 TF -> cost was dispatch
// overhead + serialization + intermediate traffic, not within-kernel structure.
__global__ __launch_bounds__(512) void enc_fused(
        const int* __restrict__ seqp, const float* __restrict__ embed,
        const ushort_t* __restrict__ W1t, const ushort_t* __restrict__ W2t,
        const float* __restrict__ b1, const float* __restrict__ b2,
        const float* __restrict__ lng, const float* __restrict__ lnb,
        const ushort_t* __restrict__ Pt,        // semt (epit adjacent: rows 256..511)
        const float* __restrict__ biasS, const float* __restrict__ biasE,
        ushort_t* __restrict__ outS, ushort_t* __restrict__ outE,
        float* __restrict__ bet_s, float* __restrict__ bet_e) {
    __shared__ __align__(16) ushort_t El[64 * 520];     // e, later h (pad: 2-way max)
    __shared__ __align__(16) ushort_t T1l[64 * 264];    // t1 slice (r3-proven pad)
    __shared__ __align__(16) ushort_t Bst[512 * 40];    // staged B tile (BK=32)
    __shared__ int toks[64];
    __shared__ float lnP[64 * 8], lnQ[64 * 8];
    __shared__ float lnM[64], lnR[64];

    int t = threadIdx.x;
    int lane = t & 63, w = t >> 6;                      // 8 waves
    int lid = lane & 15, quad = lane >> 4;
    int m0 = blockIdx.x * 64;

    // P0: tokens + gather embed -> El bf16 (one time)
    if (t < 64) toks[t] = seqp[m0 + t];
    {
        int r = t >> 3, c0 = (t & 7) * 64;
        const float* e = embed + (size_t)seqp[m0 + r] * H + c0;
        #pragma unroll
        for (int j = 0; j < 8; ++j) {
            float4 a = *(const float4*)(e + j * 8);
            float4 bq = *(const float4*)(e + j * 8 + 4);
            short8 sv;
            sv[0] = (short)f2bf(a.x);  sv[1] = (short)f2bf(a.y);
            sv[2] = (short)f2bf(a.z);  sv[3] = (short)f2bf(a.w);
            sv[4] = (short)f2bf(bq.x); sv[5] = (short)f2bf(bq.y);
            sv[6] = (short)f2bf(bq.z); sv[7] = (short)f2bf(bq.w);
            *(short8*)&El[r * 520 + c0 + j * 8] = sv;
        }
    }

    f32x4 acc2[4][4];                                   // x accumulator (64x512/8w)
    #pragma unroll
    for (int i = 0; i < 4; ++i)
        #pragma unroll
        for (int j = 0; j < 4; ++j)
            acc2[i][j] = (f32x4){0.f, 0.f, 0.f, 0.f};
    __syncthreads();

    for (int s = 0; s < 4; ++s) {
        // -------- GEMM1: t1_s[64x256] = relu(e @ W1t-slice + b1_s) ----------------
        f32x4 acc1[4][2];
        #pragma unroll
        for (int i = 0; i < 4; ++i)
            #pragma unroll
            for (int j = 0; j < 2; ++j)
                acc1[i][j] = (f32x4){0.f, 0.f, 0.f, 0.f};
        for (int kc = 0; kc < 16; ++kc) {
            {   // stage W1t rows s*256..+256, k window 32 (2 short8/thread)
                int r = t >> 1, ko = (t & 1) * 16;
                const ushort_t* src = W1t + (size_t)(s * 256 + r) * 512 + kc * 32 + ko;
                *(short8*)&Bst[r * 40 + ko]     = *(const short8*)(src);
                *(short8*)&Bst[r * 40 + ko + 8] = *(const short8*)(src + 8);
            }
            __syncthreads();
            short8 af[4], bfr[2];
            #pragma unroll
            for (int i = 0; i < 4; ++i)
                af[i] = *(const short8*)&El[(i * 16 + lid) * 520 + kc * 32 + quad * 8];
            #pragma unroll
            for (int i = 0; i < 2; ++i)
                bfr[i] = *(const short8*)&Bst[(w * 32 + i * 16 + lid) * 40 + quad * 8];
            #pragma unroll
            for (int mt = 0; mt < 4; ++mt)
                #pragma unroll
                for (int nt = 0; nt < 2; ++nt)
                    acc1[mt][nt] = __builtin_amdgcn_mfma_f32_16x16x32_bf16(
                        af[mt], bfr[nt], acc1[mt][nt], 0, 0, 0);
            __syncthreads();
        }
        // t1 = relu(acc1 + b1) -> T1l (bf16, same rounding as old t1c path)
        #pragma unroll
        for (int mt = 0; mt < 4; ++mt)
            #pragma unroll
            for (int nt = 0; nt < 2; ++nt) {
                int col = w * 32 + nt * 16 + lid;
                float bc = b1[s * 256 + col];
                #pragma unroll
                for (int rg = 0; rg < 4; ++rg) {
                    int row = mt * 16 + quad * 4 + rg;
                    T1l[row * 264 + col] = f2bf(fmaxf(acc1[mt][nt][rg] + bc, 0.f));
                }
            }
        // -------- GEMM2 partial: x += t1_s @ W2t[:, s-slice] ----------------------
        for (int kc = 0; kc < 8; ++kc) {
            {   // stage W2t rows 0..511, k = s*256 + kc*32 (4 short8/thread)
                const ushort_t* src = W2t + (size_t)t * 1024 + s * 256 + kc * 32;
                #pragma unroll
                for (int j = 0; j < 4; ++j)
                    *(short8*)&Bst[t * 40 + j * 8] = *(const short8*)(src + j * 8);
            }
            __syncthreads();                    // also covers T1l writes at kc==0
            short8 af[4], bfr[4];
            #pragma unroll
            for (int i = 0; i < 4; ++i)
                af[i] = *(const short8*)&T1l[(i * 16 + lid) * 264 + kc * 32 + quad * 8];
            #pragma unroll
            for (int i = 0; i < 4; ++i)
                bfr[i] = *(const short8*)&Bst[(w * 64 + i * 16 + lid) * 40 + quad * 8];
            #pragma unroll
            for (int mt = 0; mt < 4; ++mt)
                #pragma unroll
                for (int nt = 0; nt < 4; ++nt)
                    acc2[mt][nt] = __builtin_amdgcn_mfma_f32_16x16x32_bf16(
                        af[mt], bfr[nt], acc2[mt][nt], 0, 0, 0);
            __syncthreads();
        }
    }

    // -------- x = acc2 + b2 + e (fp32 residual, re-read like old gemm_ffn2) ------
    #pragma unroll
    for (int mt = 0; mt < 4; ++mt)
        #pragma unroll
        for (int rg = 0; rg < 4; ++rg) {
            int row = mt * 16 + quad * 4 + rg;
            const float* er = embed + (size_t)toks[row] * H;
            #pragma unroll
            for (int nt = 0; nt < 4; ++nt) {
                int col = w * 64 + nt * 16 + lid;
                acc2[mt][nt][rg] += b2[col] + er[col];
            }
        }
    // -------- LayerNorm: cross-wave reduce (shuffle over lid, LDS over waves) ----
    #pragma unroll
    for (int mt = 0; mt < 4; ++mt)
        #pragma unroll
        for (int rg = 0; rg < 4; ++rg) {
            float sv = 0.f, qv = 0.f;
            #pragma unroll
            for (int nt = 0; nt < 4; ++nt) {
                float v = acc2[mt][nt][rg];
                sv += v; qv += v * v;
            }
            #pragma unroll
            for (int d = 1; d < 16; d <<= 1) {
                sv += __shfl_xor(sv, d);
                qv += __shfl_xor(qv, d);
            }
            int row = mt * 16 + quad * 4 + rg;
            if (lid == 0) { lnP[row * 8 + w] = sv; lnQ[row * 8 + w] = qv; }
        }
    __syncthreads();
    if (t < 64) {
        float sv = 0.f, qv = 0.f;
        #pragma unroll
        for (int j = 0; j < 8; ++j) { sv += lnP[t * 8 + j]; qv += lnQ[t * 8 + j]; }
        float mu = sv * (1.f / 512.f);
        float var = qv * (1.f / 512.f) - mu * mu;
        lnM[t] = mu;
        lnR[t] = rsqrtf(var + 1e-5f);
    }
    __syncthreads();
    // h -> El (overwrite e; e no longer needed)
    #pragma unroll
    for (int mt = 0; mt < 4; ++mt)
        #pragma unroll
        for (int rg = 0; rg < 4; ++rg) {
            int row = mt * 16 + quad * 4 + rg;
            float mu = lnM[row], rs = lnR[row];
            #pragma unroll
            for (int nt = 0; nt < 4; ++nt) {
                int col = w * 64 + nt * 16 + lid;
                El[row * 520 + col] =
                    f2bf((acc2[mt][nt][rg] - mu) * rs * lng[col] + lnb[col]);
            }
        }
    __syncthreads();

    // -------- proj: [ks|ke] = h @ Pt^T + bias (Pt rows 0..511 = sem|epi) ---------
    f32x4 acc3[4][4];
    #pragma unroll
    for (int i = 0; i < 4; ++i)
        #pragma unroll
        for (int j = 0; j < 4; ++j)
            acc3[i][j] = (f32x4){0.f, 0.f, 0.f, 0.f};
    for (int kc = 0; kc < 16; ++kc) {
        {
            const ushort_t* src = Pt + (size_t)t * 512 + kc * 32;
            #pragma unroll
            for (int j = 0; j < 4; ++j)
                *(short8*)&Bst[t * 40 + j * 8] = *(const short8*)(src + j * 8);
        }
        __syncthreads();
        short8 af[4], bfr[4];
        #pragma unroll
        for (int i = 0; i < 4; ++i)
            af[i] = *(const short8*)&El[(i * 16 + lid) * 520 + kc * 32 + quad * 8];
        #pragma unroll
        for (int i = 0; i < 4; ++i)
            bfr[i] = *(const short8*)&Bst[(w * 64 + i * 16 + lid) * 40 + quad * 8];
        #pragma unroll
        for (int mt = 0; mt < 4; ++mt)
            #pragma unroll
            for (int nt = 0; nt < 4; ++nt)
                acc3[mt][nt] = __builtin_amdgcn_mfma_f32_16x16x32_bf16(
                    af[mt], bfr[nt], acc3[mt][nt], 0, 0, 0);
        __syncthreads();
    }
    // epilogue: write ks/ke bf16 + fused beta (sum of squares of ROUNDED k)
    {
        const float* bb = (w < 4) ? (biasS + w * 64) : (biasE + (w - 4) * 64);
        ushort_t* op = (w < 4) ? outS : outE;
        int cbase = (w < 4) ? (w * 64) : ((w - 4) * 64);
        #pragma unroll
        for (int mt = 0; mt < 4; ++mt)
            #pragma unroll
            for (int rg = 0; rg < 4; ++rg) {
                int row = mt * 16 + quad * 4 + rg;
                float sq = 0.f;
                #pragma unroll
                for (int nt = 0; nt < 4; ++nt) {
                    int c = nt * 16 + lid;
                    ushort_t hv = f2bf(acc3[mt][nt][rg] + bb[c]);
                    op[(size_t)(m0 + row) * HALFD + cbase + c] = hv;
                    float fv = bf2f(hv);
                    sq += fv * fv;
                }
                #pragma unroll
                for (int d = 1; d < 16; d <<= 1) sq += __shfl_xor(sq, d);
                if (lid == 0) lnP[row * 8 + w] = sq;    // reuse lnP for beta partials
            }
        __syncthreads();
        if (t < 128) {
            int row = t & 63;
            int w0 = (t < 64) ? 0 : 4;
            float sv = lnP[row * 8 + w0] + lnP[row * 8 + w0 + 1]
                     + lnP[row * 8 + w0 + 2] + lnP[row * 8 + w0 + 3];
            float* bout = (t < 64) ? bet_s : bet_e;
            bout[m0 + row] = sv + 1e-6f;
        }
    }
}

// ================= chunked delta-rule: Tinv precompute (barrier-free fsub) ========
__global__ __launch_bounds__(256) void tinv_kernel(
        const ushort_t* __restrict__ ks, const ushort_t* __restrict__ ke,
        const float* __restrict__ beta_s, const float* __restrict__ beta_e,
        ushort_t* __restrict__ Dg) {
    __shared__ __align__(16) ushort_t Kl[64][280];
    __shared__ __align__(16) ushort_t LmT[4][64][66];   // LmT[pp][j][i] = L[i][j]
    __shared__ float betsl[4][64];

    int t = threadIdx.x;
    int lane = t & 63, wv = t >> 6;
    int lid = lane & 15, quad = lane >> 4;
    int blk0 = blockIdx.x * 4;
    const float invL = 1.0f / 1024.0f;

    for (int pp = 0; pp < 4; ++pp) {
        int p = blk0 + pp;
        int ch = p & 15, bm = p >> 4;
        int mat = bm & 1, b = bm >> 1;
        const ushort_t* Kp = (mat ? ke : ks) + ((size_t)b * LSEQ + ch * 64) * HALFD;
        const float* Bp = (mat ? beta_e : beta_s) + (size_t)b * LSEQ + ch * 64;

        __syncthreads();                    // Kl free (prev pp's MFMA reads done)
        {   // stage K chunk (64 x 256 bf16)
            int j = t >> 2, c0 = (t & 3) * 64;
            const ushort_t* src = Kp + (size_t)j * HALFD + c0;
            #pragma unroll
            for (int x = 0; x < 8; ++x)
                *(short8*)&Kl[j][c0 + x * 8] = *(const short8*)(src + x * 8);
        }
        if (t < 64) betsl[pp][t] = Bp[t];
        __syncthreads();

        // G = K K^T; wave wv owns rows wv*16..+16
        f32x4 g[4];
        #pragma unroll
        for (int i = 0; i < 4; ++i) g[i] = (f32x4){0.f, 0.f, 0.f, 0.f};
        #pragma unroll
        for (int kc = 0; kc < 8; ++kc) {
            short8 af = *(const short8*)&Kl[wv * 16 + lid][kc * 32 + quad * 8];
            #pragma unroll
            for (int nt = 0; nt < 4; ++nt) {
                short8 bq = *(const short8*)&Kl[nt * 16 + lid][kc * 32 + quad * 8];
                g[nt] = __builtin_amdgcn_mfma_f32_16x16x32_bf16(af, bq, g[nt], 0, 0, 0);
            }
        }
        #pragma unroll
        for (int nt = 0; nt < 4; ++nt)
            #pragma unroll
            for (int rg = 0; rg < 4; ++rg) {
                int i = wv * 16 + quad * 4 + rg;     // row of L
                int j = nt * 16 + lid;               // col of L
                int s = ch * 64 + i;
                float wgt = mat ? (float)(s + 1) * invL : 1.0f;
                if (s >= 1023) wgt = 0.f;            // padding step
                float wb = wgt / betsl[pp][i];
                LmT[pp][j][i] = f2bf((j < i) ? g[nt][rg] * wb : 0.f);
            }
    }
    __syncthreads();                        // all LmT ready

    // barrier-free fsub: wave wv owns problem blk0+wv; lane owns column `lane`
    const ushort_t (*Lp)[66] = LmT[wv];
    float a[64];
    #pragma unroll
    for (int x = 0; x < 32; ++x) {          // a[i] = -L[i][lane] = -LmT[lane][i]
        uint_t u = *(const uint_t*)&Lp[lane][x * 2];
        a[x * 2]     = -bflo(u);
        a[x * 2 + 1] = -bfhi(u);
    }
    #pragma unroll
    for (int j = 0; j < 63; ++j) {
        float dj = a[j];
        const ushort_t* rowj = Lp[j];
        #pragma unroll
        for (int ii = (j + 1) & ~1; ii < 64; ii += 2) {
            uint_t u = *(const uint_t*)&rowj[ii];    // wave-uniform broadcast
            if (ii > j) a[ii] -= bflo(u) * dj;
            a[ii + 1]        -= bfhi(u) * dj;
        }
    }
    size_t pbase = (size_t)(blk0 + wv) * 4096;
    #pragma unroll
    for (int i = 0; i < 64; ++i)
        Dg[pbase + (size_t)i * 64 + lane] = f2bf(a[i]);
}

// ================= chunked delta-rule scan (MFMA) — r3 version (proven ~145 us) ===
__global__ __launch_bounds__(512) void scan_kernel(
        const ushort_t* __restrict__ ks, const ushort_t* __restrict__ ke,
        const float* __restrict__ beta_s, const float* __restrict__ beta_e,
        const ushort_t* __restrict__ Dg, float* __restrict__ c) {
    int blk = blockIdx.x;
    int b = blk >> 2, mat = (blk >> 1) & 1, half = blk & 1;
    const ushort_t* Kp = (mat ? ke : ks) + (size_t)b * LSEQ * HALFD;
    const float* Bp = (mat ? beta_e : beta_s) + (size_t)b * LSEQ;
    const ushort_t* Dp = Dg + (size_t)(b * 2 + mat) * 16 * 4096;

    __shared__ __align__(16) ushort_t Kl[64][264];      // K chunk [j][c]
    __shared__ __align__(16) ushort_t MK[33792];        // union: Ml[128][264] | Kt[256][72]
    __shared__ __align__(16) ushort_t RHSl[128][72];    // RHS^T [r][j']
    __shared__ __align__(16) ushort_t Ul[128][72];      // U^T [r][j]
    __shared__ __align__(16) ushort_t Dl[64][72];       // Tinv - I [j][j']
    __shared__ float bets[LSEQ];

    ushort_t (*Ml)[264] = (ushort_t(*)[264])MK;
    ushort_t (*Kt)[72]  = (ushort_t(*)[72])MK;

    int t = threadIdx.x;
    int lane = t & 63, wid = t >> 6;
    int lid = lane & 15, quad = lane >> 4;
    int wm  = (wid & 1) * 64, wn  = (wid >> 1) * 64;    // GEMM3/M org: 128x256 tile
    int wm1 = (wid & 1) * 64, wn1 = (wid >> 1) * 16;    // GEMM1/2 org: 128x64 tile

    #pragma unroll
    for (int i = 0; i < 2; ++i) bets[t + i * 512] = Bp[t + i * 512];

    f32x4 acc[4][4];
    #pragma unroll
    for (int i = 0; i < 4; ++i)
        #pragma unroll
        for (int j = 0; j < 4; ++j)
            acc[i][j] = (f32x4){0.f, 0.f, 0.f, 0.f};

    // K staging: thread t -> row sj, 4 x short8 at cols (t&7)*8 + x*64 (coalesced)
    int sj = t >> 3, scb = (t & 7) * 8;
    short8 pf[4];
    {
        const ushort_t* kr = Kp + (size_t)sj * HALFD + scb;
        #pragma unroll
        for (int x = 0; x < 4; ++x) pf[x] = *(const short8*)(kr + x * 64);
    }
    short8 dpf = *(const short8*)(Dp + t * 8);
    const float invL = 1.0f / 1024.0f;

    for (int ch = 0; ch < 16; ++ch) {
        __syncthreads();                       // F: prior-chunk LDS reads done
        #pragma unroll
        for (int x = 0; x < 4; ++x) *(short8*)&Kl[sj][scb + x * 64] = pf[x];
        *(short8*)&Dl[t >> 3][(t & 7) * 8] = dpf;
        // M_hi -> Ml
        #pragma unroll
        for (int mt = 0; mt < 4; ++mt)
            #pragma unroll
            for (int nt = 0; nt < 4; ++nt)
                #pragma unroll
                for (int rg = 0; rg < 4; ++rg)
                    Ml[wm + mt * 16 + quad * 4 + rg][wn + nt * 16 + lid] =
                        f2bf(acc[mt][nt][rg]);
        // prefetch next chunk
        int nch = (ch + 1 < 16) ? ch + 1 : 15;
        {
            const ushort_t* kr = Kp + ((size_t)nch * 64 + sj) * HALFD + scb;
            #pragma unroll
            for (int x = 0; x < 4; ++x) pf[x] = *(const short8*)(kr + x * 64);
            dpf = *(const short8*)(Dp + (size_t)nch * 4096 + t * 8);
        }
        __syncthreads();                       // A

        // GEMM1 hi: P0^T[r,i] += sum_c Mhi[r,c] K[i,c]
        f32x4 p0[4];
        #pragma unroll
        for (int i = 0; i < 4; ++i) p0[i] = (f32x4){0.f, 0.f, 0.f, 0.f};
        #pragma unroll
        for (int kc = 0; kc < 8; ++kc) {
            short8 bq = *(const short8*)&Kl[wn1 + lid][kc * 32 + quad * 8];
            #pragma unroll
            for (int mt = 0; mt < 4; ++mt) {
                short8 aq = *(const short8*)&Ml[wm1 + mt * 16 + lid][kc * 32 + quad * 8];
                p0[mt] = __builtin_amdgcn_mfma_f32_16x16x32_bf16(aq, bq, p0[mt], 0, 0, 0);
            }
        }
        __syncthreads();                       // B: Ml(hi) reads done
        // M_lo -> Ml
        #pragma unroll
        for (int mt = 0; mt < 4; ++mt)
            #pragma unroll
            for (int nt = 0; nt < 4; ++nt)
                #pragma unroll
                for (int rg = 0; rg < 4; ++rg) {
                    float v = acc[mt][nt][rg];
                    Ml[wm + mt * 16 + quad * 4 + rg][wn + nt * 16 + lid] =
                        f2bf(v - bf2f(f2bf(v)));
                }
        __syncthreads();                       // C
        // GEMM1 lo
        #pragma unroll
        for (int kc = 0; kc < 8; ++kc) {
            short8 bq = *(const short8*)&Kl[wn1 + lid][kc * 32 + quad * 8];
            #pragma unroll
            for (int mt = 0; mt < 4; ++mt) {
                short8 aq = *(const short8*)&Ml[wm1 + mt * 16 + lid][kc * 32 + quad * 8];
                p0[mt] = __builtin_amdgcn_mfma_f32_16x16x32_bf16(aq, bq, p0[mt], 0, 0, 0);
            }
        }
        // RHS: rhs[r,i] = w_i*k_i[hr] - (w_i/beta_i)*P0^T[r,i]
        int iB = wn1 + lid;
        int s = ch * 64 + iB;
        float wgt = mat ? (float)(s + 1) * invL : 1.0f;
        if (s >= 1023) wgt = 0.f;
        float wb = wgt / bets[s];
        float rhsf[4][4];
        #pragma unroll
        for (int mt = 0; mt < 4; ++mt)
            #pragma unroll
            for (int rg = 0; rg < 4; ++rg) {
                int r = wm1 + mt * 16 + quad * 4 + rg;
                float kv = bf2f(Kl[iB][half * 128 + r]);
                float rv = wgt * kv - wb * p0[mt][rg];
                rhsf[mt][rg] = rv;
                RHSl[r][iB] = f2bf(rv);
            }
        __syncthreads();                       // D: RHS ready; Ml region free

        // build Kt[c][j] = K[j][c] into the (free) Ml region
        {
            int c0 = wid * 32;
            #pragma unroll
            for (int rr = 0; rr < 4; ++rr) {
                short8 kv8 = *(const short8*)&Kl[lane][c0 + rr * 8];
                #pragma unroll
                for (int x = 0; x < 8; ++x)
                    Kt[c0 + rr * 8 + x][lane] = (ushort_t)kv8[x];
            }
        }
        // GEMM2: corr[r,j] = sum_j' RHS^T[r,j'] * D[j,j']
        f32x4 uf[4];
        #pragma unroll
        for (int i = 0; i < 4; ++i) uf[i] = (f32x4){0.f, 0.f, 0.f, 0.f};
        #pragma unroll
        for (int kc = 0; kc < 2; ++kc) {
            short8 bq = *(const short8*)&Dl[wn1 + lid][kc * 32 + quad * 8];
            #pragma unroll
            for (int mt = 0; mt < 4; ++mt) {
                short8 aq = *(const short8*)&RHSl[wm1 + mt * 16 + lid][kc * 32 + quad * 8];
                uf[mt] = __builtin_amdgcn_mfma_f32_16x16x32_bf16(aq, bq, uf[mt], 0, 0, 0);
            }
        }
        // u = corr + RHS (exact fp32 RHS from regs; frag positions identical)
        #pragma unroll
        for (int mt = 0; mt < 4; ++mt)
            #pragma unroll
            for (int rg = 0; rg < 4; ++rg) {
                int r = wm1 + mt * 16 + quad * 4 + rg;
                Ul[r][wn1 + lid] = f2bf(uf[mt][rg] + rhsf[mt][rg]);
            }
        __syncthreads();                       // E: Kt + U(hi) ready
        // GEMM3 hi: M += Uhi^T * K
        #pragma unroll
        for (int kc = 0; kc < 2; ++kc) {
            short8 bq4[4];
            #pragma unroll
            for (int nt = 0; nt < 4; ++nt)
                bq4[nt] = *(const short8*)&Kt[wn + nt * 16 + lid][kc * 32 + quad * 8];
            #pragma unroll
            for (int mt = 0; mt < 4; ++mt) {
                short8 aq = *(const short8*)&Ul[wm + mt * 16 + lid][kc * 32 + quad * 8];
                #pragma unroll
                for (int nt = 0; nt < 4; ++nt)
                    acc[mt][nt] = __builtin_amdgcn_mfma_f32_16x16x32_bf16(
                        aq, bq4[nt], acc[mt][nt], 0, 0, 0);
            }
        }
        __syncthreads();                       // E2: Ul(hi) reads done
        #pragma unroll
        for (int mt = 0; mt < 4; ++mt)
            #pragma unroll
            for (int rg = 0; rg < 4; ++rg) {
                int r = wm1 + mt * 16 + quad * 4 + rg;
                float u = uf[mt][rg] + rhsf[mt][rg];
                Ul[r][wn1 + lid] = f2bf(u - bf2f(f2bf(u)));
            }
        __syncthreads();                       // E3
        // GEMM3 lo
        #pragma unroll
        for (int kc = 0; kc < 2; ++kc) {
            short8 bq4[4];
            #pragma unroll
            for (int nt = 0; nt < 4; ++nt)
                bq4[nt] = *(const short8*)&Kt[wn + nt * 16 + lid][kc * 32 + quad * 8];
            #pragma unroll
            for (int mt = 0; mt < 4; ++mt) {
                short8 aq = *(const short8*)&Ul[wm + mt * 16 + lid][kc * 32 + quad * 8];
                #pragma unroll
                for (int nt = 0; nt < 4; ++nt)
                    acc[mt][nt] = __builtin_amdgcn_mfma_f32_16x16x32_bf16(
                        aq, bq4[nt], acc[mt][nt], 0, 0, 0);
            }
        }
    }

    // final matvec: c[hr] = sum_c M[hr,c] * k[1023][c]  (k[1023] = Kl row 63)
    __syncthreads();
    float* vsc = (float*)RHSl;                 // 4 x 128 scratch
    float kvv[4];
    #pragma unroll
    for (int nt = 0; nt < 4; ++nt)
        kvv[nt] = bf2f(Kl[63][wn + nt * 16 + lid]);
    #pragma unroll
    for (int mt = 0; mt < 4; ++mt)
        #pragma unroll
        for (int rg = 0; rg < 4; ++rg) {
            float p = acc[mt][0][rg] * kvv[0] + acc[mt][1][rg] * kvv[1]
                    + acc[mt][2][rg] * kvv[2] + acc[mt][3][rg] * kvv[3];
            p += __shfl_xor(p, 1); p += __shfl_xor(p, 2);
            p += __shfl_xor(p, 4); p += __shfl_xor(p, 8);
            if (lid == 0)
                vsc[(wid >> 1) * 128 + wm + mt * 16 + quad * 4 + rg] = p;
        }
    __syncthreads();
    if (t < 128) {
        float sum = vsc[t] + vsc[128 + t] + vsc[256 + t] + vsc[384 + t];
        c[(size_t)b * 512 + mat * 256 + half * 128 + t] = sum;
    }
}

// ---------------- output GEMM: out[64x32000] = c[64x512] @ W[512x32000] + b -------
__global__ __launch_bounds__(512) void out_gemm(
        const float* __restrict__ c, const float* __restrict__ W,
        const float* __restrict__ bias, float* __restrict__ out) {
    __shared__ __align__(16) float cl[16][512];
    int t = threadIdx.x;
    int lane = t & 63, w = t >> 6;                    // 8 waves
    int cb = blockIdx.x * 256;                        // 125*256 = 32000
    int rb = blockIdx.y * 16;                         // 4*16 = 64 rows

    #pragma unroll
    for (int i = 0; i < 4; ++i) {
        int idx = t + i * 512;                        // float4 index
        int row = idx >> 7, c4 = (idx & 127) * 4;
        *(float4*)&cl[row][c4] = *(const float4*)(c + (size_t)(rb + row) * 512 + c4);
    }
    __syncthreads();

    const float* wp = W + cb + lane * 4;
    int r0 = w * 2;
    f32x4 a0 = (f32x4){0.f, 0.f, 0.f, 0.f};
    f32x4 a1 = (f32x4){0.f, 0.f, 0.f, 0.f};

    #pragma unroll 2
    for (int k = 0; k < 512; k += 4) {
        f32x4 w0 = *(const f32x4*)(wp + (size_t)(k + 0) * V);
        f32x4 w1 = *(const f32x4*)(wp + (size_t)(k + 1) * V);
        f32x4 w2 = *(const f32x4*)(wp + (size_t)(k + 2) * V);
        f32x4 w3 = *(const f32x4*)(wp + (size_t)(k + 3) * V);
        f32x4 ca = *(const f32x4*)&cl[r0][k];
        f32x4 cb4 = *(const f32x4*)&cl[r0 + 1][k];
        a0 += ca[0] * w0; a0 += ca[1] * w1; a0 += ca[2] * w2; a0 += ca[3] * w3;
        a1 += cb4[0] * w0; a1 += cb4[1] * w1; a1 += cb4[2] * w2; a1 += cb4[3] * w3;
    }
    f32x4 bv = *(const f32x4*)(bias + cb + lane * 4);
    *(f32x4*)(out + (size_t)(rb + r0) * V + cb + lane * 4) = a0 + bv;
    *(f32x4*)(out + (size_t)(rb + r0 + 1) * V + cb + lane * 4) = a1 + bv;
}

// ---------------- launch ----------------------------------------------------------
extern "C" void kernel_launch(void* const* d_in, const int* in_sizes, int n_in,
                              void* d_out, int out_size, void* d_ws, size_t ws_size,
                              hipStream_t stream) {
    const int*   seq    = (const int*)d_in[0];
    const float* embed  = (const float*)d_in[1];
    const float* ff_w1  = (const float*)d_in[2];
    const float* ff_b1  = (const float*)d_in[3];
    const float* ff_w2  = (const float*)d_in[4];
    const float* ff_b2  = (const float*)d_in[5];
    const float* ln_g   = (const float*)d_in[6];
    const float* ln_b   = (const float*)d_in[7];
    const float* sem_w  = (const float*)d_in[8];
    const float* sem_b  = (const float*)d_in[9];
    const float* epi_w  = (const float*)d_in[10];
    const float* epi_b  = (const float*)d_in[11];
    const float* out_w  = (const float*)d_in[12];
    const float* out_b  = (const float*)d_in[13];
    float* outp = (float*)d_out;

    // workspace: 87.2 MB total (no encoder intermediates anymore)
    char* w = (char*)d_ws;
    size_t off = 0;
    ushort_t* ks_bf = (ushort_t*)(w + off); off += 33554432;          // 65536x256 bf16
    ushort_t* ke_bf = (ushort_t*)(w + off); off += 33554432;
    ushort_t* w1t   = (ushort_t*)(w + off); off += 1048576;
    ushort_t* w2t   = (ushort_t*)(w + off); off += 1048576;
    ushort_t* semt  = (ushort_t*)(w + off); off += 262144;            // semt|epit adjacent
    ushort_t* epit  = (ushort_t*)(w + off); off += 262144;
    float*    bet_s = (float*)(w + off);    off += 262144;
    float*    bet_e = (float*)(w + off);    off += 262144;
    float*    cbuf  = (float*)(w + off);    off += 131072;
    ushort_t* Dbuf  = (ushort_t*)(w + off); off += 16777216;          // Tinv-I

    // weight prep (bf16 + transpose)
    transpose_cvt<<<dim3(1024 / 32, 512 / 32), 256, 0, stream>>>(ff_w1, w1t, 512, 1024);
    transpose_cvt<<<dim3(512 / 32, 1024 / 32), 256, 0, stream>>>(ff_w2, w2t, 1024, 512);
    transpose_cvt<<<dim3(256 / 32, 512 / 32), 256, 0, stream>>>(sem_w, semt, 512, 256);
    transpose_cvt<<<dim3(256 / 32, 512 / 32), 256, 0, stream>>>(epi_w, epit, 512, 256);

    // fully fused encoder: embed-gather + FFN + residual + LN + proj + beta
    enc_fused<<<1024, 512, 0, stream>>>(
        seq, embed, w1t, w2t, ff_b1, ff_b2, ln_g, ln_b,
        semt, sem_b, epi_b, ks_bf, ke_bf, bet_s, bet_e);

    tinv_kernel<<<512, 256, 0, stream>>>(ks_bf, ke_bf, bet_s, bet_e, Dbuf);
    scan_kernel<<<256, 512, 0, stream>>>(ks_bf, ke_bf, bet_s, bet_e, Dbuf, cbuf);

    out_gemm<<<dim3(125, 4), 512, 0, stream>>>(cbuf, out_w, out_b, outp);
}

// Round 9
// 818.435 us; speedup vs baseline: 1.1762x; 1.1762x over previous
//
#include <hip/hip_runtime.h>

typedef unsigned short ushort_t;
typedef unsigned int uint_t;
typedef __attribute__((ext_vector_type(8))) short short8;
typedef __attribute__((ext_vector_type(4))) float f32x4;

static constexpr int V = 32000, H = 512, HALFD = 256, LSEQ = 1024, BB = 64;

__device__ __forceinline__ ushort_t f2bf(float f) {
    uint_t u = __float_as_uint(f);
    u = (u + 0x7FFFu + ((u >> 16) & 1u)) >> 16;
    return (ushort_t)u;
}
__device__ __forceinline__ float bf2f(ushort_t u) {
    return __uint_as_float(((uint_t)u) << 16);
}
__device__ __forceinline__ float bflo(uint_t u) { return __uint_as_float(u << 16); }
__device__ __forceinline__ float bfhi(uint_t u) { return __uint_as_float(u & 0xffff0000u); }

// ---------------- weight transpose + fp32->bf16 convert: Wt[n][k] = bf16(W[k][n]) --
__global__ void transpose_cvt(const float* __restrict__ W, ushort_t* __restrict__ Wt,
                              int K, int N) {
    __shared__ float tile[32][33];
    int k0 = blockIdx.y * 32, n0 = blockIdx.x * 32;
    int tx = threadIdx.x & 31, ty = threadIdx.x >> 5;   // 256 threads: ty 0..7
    #pragma unroll
    for (int i = 0; i < 32; i += 8)
        tile[ty + i][tx] = W[(size_t)(k0 + ty + i) * N + n0 + tx];
    __syncthreads();
    #pragma unroll
    for (int i = 0; i < 32; i += 8)
        Wt[(size_t)(n0 + ty + i) * K + k0 + tx] = f2bf(tile[tx][ty + i]);
}

// ================= fully fused encoder, v2: barrier-free k-loops ==================
// r8 post-mortem: v1 had ~230 barriers/block (weight staging per kc) with 1
// block/CU -> every L2 weight-fetch latency fully exposed (MfmaUtil 12.5%).
// v2: B-fragments load DIRECTLY from L2-resident weights into registers with
// one-step prefetch (r2 out_gemm lesson); LDS holds only block-local A (El, T1l),
// read-only inside k-loops -> ZERO barriers in k-loops, ~14/block total.
__global__ __launch_bounds__(512) void enc_fused(
        const int* __restrict__ seqp, const float* __restrict__ embed,
        const ushort_t* __restrict__ W1t, const ushort_t* __restrict__ W2t,
        const float* __restrict__ b1, const float* __restrict__ b2,
        const float* __restrict__ lng, const float* __restrict__ lnb,
        const ushort_t* __restrict__ Pt,        // semt (epit adjacent: rows 256..511)
        const float* __restrict__ biasS, const float* __restrict__ biasE,
        ushort_t* __restrict__ outS, ushort_t* __restrict__ outE,
        float* __restrict__ bet_s, float* __restrict__ bet_e) {
    __shared__ __align__(16) ushort_t El[64 * 520];     // e, later h
    __shared__ __align__(16) ushort_t T1l[64 * 264];    // t1 slice
    __shared__ int toks[64];
    __shared__ float lnP[64 * 8], lnQ[64 * 8];
    __shared__ float lnM[64], lnR[64];

    int t = threadIdx.x;
    int lane = t & 63, w = t >> 6;                      // 8 waves
    int lid = lane & 15, quad = lane >> 4;
    int m0 = blockIdx.x * 64;

    // P0: tokens + gather embed -> El bf16 (one time)
    if (t < 64) toks[t] = seqp[m0 + t];
    {
        int r = t >> 3, c0 = (t & 7) * 64;
        const float* e = embed + (size_t)seqp[m0 + r] * H + c0;
        #pragma unroll
        for (int j = 0; j < 8; ++j) {
            float4 a = *(const float4*)(e + j * 8);
            float4 bq = *(const float4*)(e + j * 8 + 4);
            short8 sv;
            sv[0] = (short)f2bf(a.x);  sv[1] = (short)f2bf(a.y);
            sv[2] = (short)f2bf(a.z);  sv[3] = (short)f2bf(a.w);
            sv[4] = (short)f2bf(bq.x); sv[5] = (short)f2bf(bq.y);
            sv[6] = (short)f2bf(bq.z); sv[7] = (short)f2bf(bq.w);
            *(short8*)&El[r * 520 + c0 + j * 8] = sv;
        }
    }

    f32x4 acc2[4][4];                                   // x accumulator (64x512/8w)
    #pragma unroll
    for (int i = 0; i < 4; ++i)
        #pragma unroll
        for (int j = 0; j < 4; ++j)
            acc2[i][j] = (f32x4){0.f, 0.f, 0.f, 0.f};
    __syncthreads();

    for (int s = 0; s < 4; ++s) {
        // -------- GEMM1: t1_s[64x256] = relu(e @ W1t-slice + b1_s) ----------------
        // B-frags: W1t rows s*256 + w*32 + nt*16 + lid, k = kc*32 + quad*8.
        f32x4 acc1[4][2];
        #pragma unroll
        for (int i = 0; i < 4; ++i)
            #pragma unroll
            for (int j = 0; j < 2; ++j)
                acc1[i][j] = (f32x4){0.f, 0.f, 0.f, 0.f};
        {
            const ushort_t* wb = W1t + (size_t)(s * 256 + w * 32 + lid) * 512 + quad * 8;
            short8 bc0 = *(const short8*)(wb);
            short8 bc1 = *(const short8*)(wb + 16 * 512);
            for (int kc = 0; kc < 16; ++kc) {
                short8 bn0 = bc0, bn1 = bc1;
                if (kc < 15) {
                    bn0 = *(const short8*)(wb + (kc + 1) * 32);
                    bn1 = *(const short8*)(wb + 16 * 512 + (kc + 1) * 32);
                }
                short8 af[4];
                #pragma unroll
                for (int i = 0; i < 4; ++i)
                    af[i] = *(const short8*)&El[(i * 16 + lid) * 520 + kc * 32 + quad * 8];
                #pragma unroll
                for (int mt = 0; mt < 4; ++mt) {
                    acc1[mt][0] = __builtin_amdgcn_mfma_f32_16x16x32_bf16(
                        af[mt], bc0, acc1[mt][0], 0, 0, 0);
                    acc1[mt][1] = __builtin_amdgcn_mfma_f32_16x16x32_bf16(
                        af[mt], bc1, acc1[mt][1], 0, 0, 0);
                }
                bc0 = bn0; bc1 = bn1;
            }
        }
        // t1 = relu(acc1 + b1) -> T1l (bf16, same rounding as original)
        #pragma unroll
        for (int mt = 0; mt < 4; ++mt)
            #pragma unroll
            for (int nt = 0; nt < 2; ++nt) {
                int col = w * 32 + nt * 16 + lid;
                float bc = b1[s * 256 + col];
                #pragma unroll
                for (int rg = 0; rg < 4; ++rg) {
                    int row = mt * 16 + quad * 4 + rg;
                    T1l[row * 264 + col] = f2bf(fmaxf(acc1[mt][nt][rg] + bc, 0.f));
                }
            }
        __syncthreads();                        // T1l ready for all waves

        // -------- GEMM2 partial: x += t1_s @ W2t[:, s-slice] ----------------------
        // B-frags: W2t rows w*64 + nt*16 + lid, k = s*256 + kc*32 + quad*8.
        {
            const ushort_t* wb = W2t + (size_t)(w * 64 + lid) * 1024 + s * 256 + quad * 8;
            short8 bc0 = *(const short8*)(wb);
            short8 bc1 = *(const short8*)(wb + 16 * 1024);
            short8 bc2 = *(const short8*)(wb + 32 * 1024);
            short8 bc3 = *(const short8*)(wb + 48 * 1024);
            for (int kc = 0; kc < 8; ++kc) {
                short8 bn0 = bc0, bn1 = bc1, bn2 = bc2, bn3 = bc3;
                if (kc < 7) {
                    bn0 = *(const short8*)(wb + (kc + 1) * 32);
                    bn1 = *(const short8*)(wb + 16 * 1024 + (kc + 1) * 32);
                    bn2 = *(const short8*)(wb + 32 * 1024 + (kc + 1) * 32);
                    bn3 = *(const short8*)(wb + 48 * 1024 + (kc + 1) * 32);
                }
                short8 af[4];
                #pragma unroll
                for (int i = 0; i < 4; ++i)
                    af[i] = *(const short8*)&T1l[(i * 16 + lid) * 264 + kc * 32 + quad * 8];
                #pragma unroll
                for (int mt = 0; mt < 4; ++mt) {
                    acc2[mt][0] = __builtin_amdgcn_mfma_f32_16x16x32_bf16(
                        af[mt], bc0, acc2[mt][0], 0, 0, 0);
                    acc2[mt][1] = __builtin_amdgcn_mfma_f32_16x16x32_bf16(
                        af[mt], bc1, acc2[mt][1], 0, 0, 0);
                    acc2[mt][2] = __builtin_amdgcn_mfma_f32_16x16x32_bf16(
                        af[mt], bc2, acc2[mt][2], 0, 0, 0);
                    acc2[mt][3] = __builtin_amdgcn_mfma_f32_16x16x32_bf16(
                        af[mt], bc3, acc2[mt][3], 0, 0, 0);
                }
                bc0 = bn0; bc1 = bn1; bc2 = bn2; bc3 = bn3;
            }
        }
        __syncthreads();                        // T1l reads done (next slice rewrites)
    }

    // -------- x = acc2 + b2 + e (fp32 residual) ----------------------------------
    #pragma unroll
    for (int mt = 0; mt < 4; ++mt)
        #pragma unroll
        for (int rg = 0; rg < 4; ++rg) {
            int row = mt * 16 + quad * 4 + rg;
            const float* er = embed + (size_t)toks[row] * H;
            #pragma unroll
            for (int nt = 0; nt < 4; ++nt) {
                int col = w * 64 + nt * 16 + lid;
                acc2[mt][nt][rg] += b2[col] + er[col];
            }
        }
    // -------- LayerNorm: cross-wave reduce (shuffle over lid, LDS over waves) ----
    #pragma unroll
    for (int mt = 0; mt < 4; ++mt)
        #pragma unroll
        for (int rg = 0; rg < 4; ++rg) {
            float sv = 0.f, qv = 0.f;
            #pragma unroll
            for (int nt = 0; nt < 4; ++nt) {
                float v = acc2[mt][nt][rg];
                sv += v; qv += v * v;
            }
            #pragma unroll
            for (int d = 1; d < 16; d <<= 1) {
                sv += __shfl_xor(sv, d);
                qv += __shfl_xor(qv, d);
            }
            int row = mt * 16 + quad * 4 + rg;
            if (lid == 0) { lnP[row * 8 + w] = sv; lnQ[row * 8 + w] = qv; }
        }
    __syncthreads();
    if (t < 64) {
        float sv = 0.f, qv = 0.f;
        #pragma unroll
        for (int j = 0; j < 8; ++j) { sv += lnP[t * 8 + j]; qv += lnQ[t * 8 + j]; }
        float mu = sv * (1.f / 512.f);
        float var = qv * (1.f / 512.f) - mu * mu;
        lnM[t] = mu;
        lnR[t] = rsqrtf(var + 1e-5f);
    }
    __syncthreads();
    // h -> El (overwrite e; e no longer needed)
    #pragma unroll
    for (int mt = 0; mt < 4; ++mt)
        #pragma unroll
        for (int rg = 0; rg < 4; ++rg) {
            int row = mt * 16 + quad * 4 + rg;
            float mu = lnM[row], rs = lnR[row];
            #pragma unroll
            for (int nt = 0; nt < 4; ++nt) {
                int col = w * 64 + nt * 16 + lid;
                El[row * 520 + col] =
                    f2bf((acc2[mt][nt][rg] - mu) * rs * lng[col] + lnb[col]);
            }
        }
    __syncthreads();

    // -------- proj: [ks|ke] = h @ Pt^T + bias (Pt rows 0..511 = sem|epi) ---------
    // B-frags: Pt rows w*64 + nt*16 + lid, k = kc*32 + quad*8. Barrier-free loop.
    f32x4 acc3[4][4];
    #pragma unroll
    for (int i = 0; i < 4; ++i)
        #pragma unroll
        for (int j = 0; j < 4; ++j)
            acc3[i][j] = (f32x4){0.f, 0.f, 0.f, 0.f};
    {
        const ushort_t* pb = Pt + (size_t)(w * 64 + lid) * 512 + quad * 8;
        short8 bc0 = *(const short8*)(pb);
        short8 bc1 = *(const short8*)(pb + 16 * 512);
        short8 bc2 = *(const short8*)(pb + 32 * 512);
        short8 bc3 = *(const short8*)(pb + 48 * 512);
        for (int kc = 0; kc < 16; ++kc) {
            short8 bn0 = bc0, bn1 = bc1, bn2 = bc2, bn3 = bc3;
            if (kc < 15) {
                bn0 = *(const short8*)(pb + (kc + 1) * 32);
                bn1 = *(const short8*)(pb + 16 * 512 + (kc + 1) * 32);
                bn2 = *(const short8*)(pb + 32 * 512 + (kc + 1) * 32);
                bn3 = *(const short8*)(pb + 48 * 512 + (kc + 1) * 32);
            }
            short8 af[4];
            #pragma unroll
            for (int i = 0; i < 4; ++i)
                af[i] = *(const short8*)&El[(i * 16 + lid) * 520 + kc * 32 + quad * 8];
            #pragma unroll
            for (int mt = 0; mt < 4; ++mt) {
                acc3[mt][0] = __builtin_amdgcn_mfma_f32_16x16x32_bf16(
                    af[mt], bc0, acc3[mt][0], 0, 0, 0);
                acc3[mt][1] = __builtin_amdgcn_mfma_f32_16x16x32_bf16(
                    af[mt], bc1, acc3[mt][1], 0, 0, 0);
                acc3[mt][2] = __builtin_amdgcn_mfma_f32_16x16x32_bf16(
                    af[mt], bc2, acc3[mt][2], 0, 0, 0);
                acc3[mt][3] = __builtin_amdgcn_mfma_f32_16x16x32_bf16(
                    af[mt], bc3, acc3[mt][3], 0, 0, 0);
            }
            bc0 = bn0; bc1 = bn1; bc2 = bn2; bc3 = bn3;
        }
    }
    // epilogue: write ks/ke bf16 + fused beta (sum of squares of ROUNDED k)
    {
        const float* bb = (w < 4) ? (biasS + w * 64) : (biasE + (w - 4) * 64);
        ushort_t* op = (w < 4) ? outS : outE;
        int cbase = (w < 4) ? (w * 64) : ((w - 4) * 64);
        #pragma unroll
        for (int mt = 0; mt < 4; ++mt)
            #pragma unroll
            for (int rg = 0; rg < 4; ++rg) {
                int row = mt * 16 + quad * 4 + rg;
                float sq = 0.f;
                #pragma unroll
                for (int nt = 0; nt < 4; ++nt) {
                    int c = nt * 16 + lid;
                    ushort_t hv = f2bf(acc3[mt][nt][rg] + bb[c]);
                    op[(size_t)(m0 + row) * HALFD + cbase + c] = hv;
                    float fv = bf2f(hv);
                    sq += fv * fv;
                }
                #pragma unroll
                for (int d = 1; d < 16; d <<= 1) sq += __shfl_xor(sq, d);
                if (lid == 0) lnP[row * 8 + w] = sq;    // reuse lnP for beta partials
            }
        __syncthreads();
        if (t < 128) {
            int row = t & 63;
            int w0 = (t < 64) ? 0 : 4;
            float sv = lnP[row * 8 + w0] + lnP[row * 8 + w0 + 1]
                     + lnP[row * 8 + w0 + 2] + lnP[row * 8 + w0 + 3];
            float* bout = (t < 64) ? bet_s : bet_e;
            bout[m0 + row] = sv + 1e-6f;
        }
    }
}

// ================= chunked delta-rule: Tinv precompute (barrier-free fsub) ========
__global__ __launch_bounds__(256) void tinv_kernel(
        const ushort_t* __restrict__ ks, const ushort_t* __restrict__ ke,
        const float* __restrict__ beta_s, const float* __restrict__ beta_e,
        ushort_t* __restrict__ Dg) {
    __shared__ __align__(16) ushort_t Kl[64][280];
    __shared__ __align__(16) ushort_t LmT[4][64][66];   // LmT[pp][j][i] = L[i][j]
    __shared__ float betsl[4][64];

    int t = threadIdx.x;
    int lane = t & 63, wv = t >> 6;
    int lid = lane & 15, quad = lane >> 4;
    int blk0 = blockIdx.x * 4;
    const float invL = 1.0f / 1024.0f;

    for (int pp = 0; pp < 4; ++pp) {
        int p = blk0 + pp;
        int ch = p & 15, bm = p >> 4;
        int mat = bm & 1, b = bm >> 1;
        const ushort_t* Kp = (mat ? ke : ks) + ((size_t)b * LSEQ + ch * 64) * HALFD;
        const float* Bp = (mat ? beta_e : beta_s) + (size_t)b * LSEQ + ch * 64;

        __syncthreads();                    // Kl free (prev pp's MFMA reads done)
        {   // stage K chunk (64 x 256 bf16)
            int j = t >> 2, c0 = (t & 3) * 64;
            const ushort_t* src = Kp + (size_t)j * HALFD + c0;
            #pragma unroll
            for (int x = 0; x < 8; ++x)
                *(short8*)&Kl[j][c0 + x * 8] = *(const short8*)(src + x * 8);
        }
        if (t < 64) betsl[pp][t] = Bp[t];
        __syncthreads();

        // G = K K^T; wave wv owns rows wv*16..+16
        f32x4 g[4];
        #pragma unroll
        for (int i = 0; i < 4; ++i) g[i] = (f32x4){0.f, 0.f, 0.f, 0.f};
        #pragma unroll
        for (int kc = 0; kc < 8; ++kc) {
            short8 af = *(const short8*)&Kl[wv * 16 + lid][kc * 32 + quad * 8];
            #pragma unroll
            for (int nt = 0; nt < 4; ++nt) {
                short8 bq = *(const short8*)&Kl[nt * 16 + lid][kc * 32 + quad * 8];
                g[nt] = __builtin_amdgcn_mfma_f32_16x16x32_bf16(af, bq, g[nt], 0, 0, 0);
            }
        }
        #pragma unroll
        for (int nt = 0; nt < 4; ++nt)
            #pragma unroll
            for (int rg = 0; rg < 4; ++rg) {
                int i = wv * 16 + quad * 4 + rg;     // row of L
                int j = nt * 16 + lid;               // col of L
                int s = ch * 64 + i;
                float wgt = mat ? (float)(s + 1) * invL : 1.0f;
                if (s >= 1023) wgt = 0.f;            // padding step
                float wb = wgt / betsl[pp][i];
                LmT[pp][j][i] = f2bf((j < i) ? g[nt][rg] * wb : 0.f);
            }
    }
    __syncthreads();                        // all LmT ready

    // barrier-free fsub: wave wv owns problem blk0+wv; lane owns column `lane`
    const ushort_t (*Lp)[66] = LmT[wv];
    float a[64];
    #pragma unroll
    for (int x = 0; x < 32; ++x) {          // a[i] = -L[i][lane] = -LmT[lane][i]
        uint_t u = *(const uint_t*)&Lp[lane][x * 2];
        a[x * 2]     = -bflo(u);
        a[x * 2 + 1] = -bfhi(u);
    }
    #pragma unroll
    for (int j = 0; j < 63; ++j) {
        float dj = a[j];
        const ushort_t* rowj = Lp[j];
        #pragma unroll
        for (int ii = (j + 1) & ~1; ii < 64; ii += 2) {
            uint_t u = *(const uint_t*)&rowj[ii];    // wave-uniform broadcast
            if (ii > j) a[ii] -= bflo(u) * dj;
            a[ii + 1]        -= bfhi(u) * dj;
        }
    }
    size_t pbase = (size_t)(blk0 + wv) * 4096;
    #pragma unroll
    for (int i = 0; i < 64; ++i)
        Dg[pbase + (size_t)i * 64 + lane] = f2bf(a[i]);
}

// ================= chunked delta-rule scan (MFMA) — r3 version (proven ~145 us) ===
__global__ __launch_bounds__(512) void scan_kernel(
        const ushort_t* __restrict__ ks, const ushort_t* __restrict__ ke,
        const float* __restrict__ beta_s, const float* __restrict__ beta_e,
        const ushort_t* __restrict__ Dg, float* __restrict__ c) {
    int blk = blockIdx.x;
    int b = blk >> 2, mat = (blk >> 1) & 1, half = blk & 1;
    const ushort_t* Kp = (mat ? ke : ks) + (size_t)b * LSEQ * HALFD;
    const float* Bp = (mat ? beta_e : beta_s) + (size_t)b * LSEQ;
    const ushort_t* Dp = Dg + (size_t)(b * 2 + mat) * 16 * 4096;

    __shared__ __align__(16) ushort_t Kl[64][264];      // K chunk [j][c]
    __shared__ __align__(16) ushort_t MK[33792];        // union: Ml[128][264] | Kt[256][72]
    __shared__ __align__(16) ushort_t RHSl[128][72];    // RHS^T [r][j']
    __shared__ __align__(16) ushort_t Ul[128][72];      // U^T [r][j]
    __shared__ __align__(16) ushort_t Dl[64][72];       // Tinv - I [j][j']
    __shared__ float bets[LSEQ];

    ushort_t (*Ml)[264] = (ushort_t(*)[264])MK;
    ushort_t (*Kt)[72]  = (ushort_t(*)[72])MK;

    int t = threadIdx.x;
    int lane = t & 63, wid = t >> 6;
    int lid = lane & 15, quad = lane >> 4;
    int wm  = (wid & 1) * 64, wn  = (wid >> 1) * 64;    // GEMM3/M org: 128x256 tile
    int wm1 = (wid & 1) * 64, wn1 = (wid >> 1) * 16;    // GEMM1/2 org: 128x64 tile

    #pragma unroll
    for (int i = 0; i < 2; ++i) bets[t + i * 512] = Bp[t + i * 512];

    f32x4 acc[4][4];
    #pragma unroll
    for (int i = 0; i < 4; ++i)
        #pragma unroll
        for (int j = 0; j < 4; ++j)
            acc[i][j] = (f32x4){0.f, 0.f, 0.f, 0.f};

    // K staging: thread t -> row sj, 4 x short8 at cols (t&7)*8 + x*64 (coalesced)
    int sj = t >> 3, scb = (t & 7) * 8;
    short8 pf[4];
    {
        const ushort_t* kr = Kp + (size_t)sj * HALFD + scb;
        #pragma unroll
        for (int x = 0; x < 4; ++x) pf[x] = *(const short8*)(kr + x * 64);
    }
    short8 dpf = *(const short8*)(Dp + t * 8);
    const float invL = 1.0f / 1024.0f;

    for (int ch = 0; ch < 16; ++ch) {
        __syncthreads();                       // F: prior-chunk LDS reads done
        #pragma unroll
        for (int x = 0; x < 4; ++x) *(short8*)&Kl[sj][scb + x * 64] = pf[x];
        *(short8*)&Dl[t >> 3][(t & 7) * 8] = dpf;
        // M_hi -> Ml
        #pragma unroll
        for (int mt = 0; mt < 4; ++mt)
            #pragma unroll
            for (int nt = 0; nt < 4; ++nt)
                #pragma unroll
                for (int rg = 0; rg < 4; ++rg)
                    Ml[wm + mt * 16 + quad * 4 + rg][wn + nt * 16 + lid] =
                        f2bf(acc[mt][nt][rg]);
        // prefetch next chunk
        int nch = (ch + 1 < 16) ? ch + 1 : 15;
        {
            const ushort_t* kr = Kp + ((size_t)nch * 64 + sj) * HALFD + scb;
            #pragma unroll
            for (int x = 0; x < 4; ++x) pf[x] = *(const short8*)(kr + x * 64);
            dpf = *(const short8*)(Dp + (size_t)nch * 4096 + t * 8);
        }
        __syncthreads();                       // A

        // GEMM1 hi: P0^T[r,i] += sum_c Mhi[r,c] K[i,c]
        f32x4 p0[4];
        #pragma unroll
        for (int i = 0; i < 4; ++i) p0[i] = (f32x4){0.f, 0.f, 0.f, 0.f};
        #pragma unroll
        for (int kc = 0; kc < 8; ++kc) {
            short8 bq = *(const short8*)&Kl[wn1 + lid][kc * 32 + quad * 8];
            #pragma unroll
            for (int mt = 0; mt < 4; ++mt) {
                short8 aq = *(const short8*)&Ml[wm1 + mt * 16 + lid][kc * 32 + quad * 8];
                p0[mt] = __builtin_amdgcn_mfma_f32_16x16x32_bf16(aq, bq, p0[mt], 0, 0, 0);
            }
        }
        __syncthreads();                       // B: Ml(hi) reads done
        // M_lo -> Ml
        #pragma unroll
        for (int mt = 0; mt < 4; ++mt)
            #pragma unroll
            for (int nt = 0; nt < 4; ++nt)
                #pragma unroll
                for (int rg = 0; rg < 4; ++rg) {
                    float v = acc[mt][nt][rg];
                    Ml[wm + mt * 16 + quad * 4 + rg][wn + nt * 16 + lid] =
                        f2bf(v - bf2f(f2bf(v)));
                }
        __syncthreads();                       // C
        // GEMM1 lo
        #pragma unroll
        for (int kc = 0; kc < 8; ++kc) {
            short8 bq = *(const short8*)&Kl[wn1 + lid][kc * 32 + quad * 8];
            #pragma unroll
            for (int mt = 0; mt < 4; ++mt) {
                short8 aq = *(const short8*)&Ml[wm1 + mt * 16 + lid][kc * 32 + quad * 8];
                p0[mt] = __builtin_amdgcn_mfma_f32_16x16x32_bf16(aq, bq, p0[mt], 0, 0, 0);
            }
        }
        // RHS: rhs[r,i] = w_i*k_i[hr] - (w_i/beta_i)*P0^T[r,i]
        int iB = wn1 + lid;
        int s = ch * 64 + iB;
        float wgt = mat ? (float)(s + 1) * invL : 1.0f;
        if (s >= 1023) wgt = 0.f;
        float wb = wgt / bets[s];
        float rhsf[4][4];
        #pragma unroll
        for (int mt = 0; mt < 4; ++mt)
            #pragma unroll
            for (int rg = 0; rg < 4; ++rg) {
                int r = wm1 + mt * 16 + quad * 4 + rg;
                float kv = bf2f(Kl[iB][half * 128 + r]);
                float rv = wgt * kv - wb * p0[mt][rg];
                rhsf[mt][rg] = rv;
                RHSl[r][iB] = f2bf(rv);
            }
        __syncthreads();                       // D: RHS ready; Ml region free

        // build Kt[c][j] = K[j][c] into the (free) Ml region
        {
            int c0 = wid * 32;
            #pragma unroll
            for (int rr = 0; rr < 4; ++rr) {
                short8 kv8 = *(const short8*)&Kl[lane][c0 + rr * 8];
                #pragma unroll
                for (int x = 0; x < 8; ++x)
                    Kt[c0 + rr * 8 + x][lane] = (ushort_t)kv8[x];
            }
        }
        // GEMM2: corr[r,j] = sum_j' RHS^T[r,j'] * D[j,j']
        f32x4 uf[4];
        #pragma unroll
        for (int i = 0; i < 4; ++i) uf[i] = (f32x4){0.f, 0.f, 0.f, 0.f};
        #pragma unroll
        for (int kc = 0; kc < 2; ++kc) {
            short8 bq = *(const short8*)&Dl[wn1 + lid][kc * 32 + quad * 8];
            #pragma unroll
            for (int mt = 0; mt < 4; ++mt) {
                short8 aq = *(const short8*)&RHSl[wm1 + mt * 16 + lid][kc * 32 + quad * 8];
                uf[mt] = __builtin_amdgcn_mfma_f32_16x16x32_bf16(aq, bq, uf[mt], 0, 0, 0);
            }
        }
        // u = corr + RHS (exact fp32 RHS from regs; frag positions identical)
        #pragma unroll
        for (int mt = 0; mt < 4; ++mt)
            #pragma unroll
            for (int rg = 0; rg < 4; ++rg) {
                int r = wm1 + mt * 16 + quad * 4 + rg;
                Ul[r][wn1 + lid] = f2bf(uf[mt][rg] + rhsf[mt][rg]);
            }
        __syncthreads();                       // E: Kt + U(hi) ready
        // GEMM3 hi: M += Uhi^T * K
        #pragma unroll
        for (int kc = 0; kc < 2; ++kc) {
            short8 bq4[4];
            #pragma unroll
            for (int nt = 0; nt < 4; ++nt)
                bq4[nt] = *(const short8*)&Kt[wn + nt * 16 + lid][kc * 32 + quad * 8];
            #pragma unroll
            for (int mt = 0; mt < 4; ++mt) {
                short8 aq = *(const short8*)&Ul[wm + mt * 16 + lid][kc * 32 + quad * 8];
                #pragma unroll
                for (int nt = 0; nt < 4; ++nt)
                    acc[mt][nt] = __builtin_amdgcn_mfma_f32_16x16x32_bf16(
                        aq, bq4[nt], acc[mt][nt], 0, 0, 0);
            }
        }
        __syncthreads();                       // E2: Ul(hi) reads done
        #pragma unroll
        for (int mt = 0; mt < 4; ++mt)
            #pragma unroll
            for (int rg = 0; rg < 4; ++rg) {
                int r = wm1 + mt * 16 + quad * 4 + rg;
                float u = uf[mt][rg] + rhsf[mt][rg];
                Ul[r][wn1 + lid] = f2bf(u - bf2f(f2bf(u)));
            }
        __syncthreads();                       // E3
        // GEMM3 lo
        #pragma unroll
        for (int kc = 0; kc < 2; ++kc) {
            short8 bq4[4];
            #pragma unroll
            for (int nt = 0; nt < 4; ++nt)
                bq4[nt] = *(const short8*)&Kt[wn + nt * 16 + lid][kc * 32 + quad * 8];
            #pragma unroll
            for (int mt = 0; mt < 4; ++mt) {
                short8 aq = *(const short8*)&Ul[wm + mt * 16 + lid][kc * 32 + quad * 8];
                #pragma unroll
                for (int nt = 0; nt < 4; ++nt)
                    acc[mt][nt] = __builtin_amdgcn_mfma_f32_16x16x32_bf16(
                        aq, bq4[nt], acc[mt][nt], 0, 0, 0);
            }
        }
    }

    // final matvec: c[hr] = sum_c M[hr,c] * k[1023][c]  (k[1023] = Kl row 63)
    __syncthreads();
    float* vsc = (float*)RHSl;                 // 4 x 128 scratch
    float kvv[4];
    #pragma unroll
    for (int nt = 0; nt < 4; ++nt)
        kvv[nt] = bf2f(Kl[63][wn + nt * 16 + lid]);
    #pragma unroll
    for (int mt = 0; mt < 4; ++mt)
        #pragma unroll
        for (int rg = 0; rg < 4; ++rg) {
            float p = acc[mt][0][rg] * kvv[0] + acc[mt][1][rg] * kvv[1]
                    + acc[mt][2][rg] * kvv[2] + acc[mt][3][rg] * kvv[3];
            p += __shfl_xor(p, 1); p += __shfl_xor(p, 2);
            p += __shfl_xor(p, 4); p += __shfl_xor(p, 8);
            if (lid == 0)
                vsc[(wid >> 1) * 128 + wm + mt * 16 + quad * 4 + rg] = p;
        }
    __syncthreads();
    if (t < 128) {
        float sum = vsc[t] + vsc[128 + t] + vsc[256 + t] + vsc[384 + t];
        c[(size_t)b * 512 + mat * 256 + half * 128 + t] = sum;
    }
}

// ---------------- output GEMM: out[64x32000] = c[64x512] @ W[512x32000] + b -------
__global__ __launch_bounds__(512) void out_gemm(
        const float* __restrict__ c, const float* __restrict__ W,
        const float* __restrict__ bias, float* __restrict__ out) {
    __shared__ __align__(16) float cl[16][512];
    int t = threadIdx.x;
    int lane = t & 63, w = t >> 6;                    // 8 waves
    int cb = blockIdx.x * 256;                        // 125*256 = 32000
    int rb = blockIdx.y * 16;                         // 4*16 = 64 rows

    #pragma unroll
    for (int i = 0; i < 4; ++i) {
        int idx = t + i * 512;                        // float4 index
        int row = idx >> 7, c4 = (idx & 127) * 4;
        *(float4*)&cl[row][c4] = *(const float4*)(c + (size_t)(rb + row) * 512 + c4);
    }
    __syncthreads();

    const float* wp = W + cb + lane * 4;
    int r0 = w * 2;
    f32x4 a0 = (f32x4){0.f, 0.f, 0.f, 0.f};
    f32x4 a1 = (f32x4){0.f, 0.f, 0.f, 0.f};

    #pragma unroll 2
    for (int k = 0; k < 512; k += 4) {
        f32x4 w0 = *(const f32x4*)(wp + (size_t)(k + 0) * V);
        f32x4 w1 = *(const f32x4*)(wp + (size_t)(k + 1) * V);
        f32x4 w2 = *(const f32x4*)(wp + (size_t)(k + 2) * V);
        f32x4 w3 = *(const f32x4*)(wp + (size_t)(k + 3) * V);
        f32x4 ca = *(const f32x4*)&cl[r0][k];
        f32x4 cb4 = *(const f32x4*)&cl[r0 + 1][k];
        a0 += ca[0] * w0; a0 += ca[1] * w1; a0 += ca[2] * w2; a0 += ca[3] * w3;
        a1 += cb4[0] * w0; a1 += cb4[1] * w1; a1 += cb4[2] * w2; a1 += cb4[3] * w3;
    }
    f32x4 bv = *(const f32x4*)(bias + cb + lane * 4);
    *(f32x4*)(out + (size_t)(rb + r0) * V + cb + lane * 4) = a0 + bv;
    *(f32x4*)(out + (size_t)(rb + r0 + 1) * V + cb + lane * 4) = a1 + bv;
}

// ---------------- launch ----------------------------------------------------------
extern "C" void kernel_launch(void* const* d_in, const int* in_sizes, int n_in,
                              void* d_out, int out_size, void* d_ws, size_t ws_size,
                              hipStream_t stream) {
    const int*   seq    = (const int*)d_in[0];
    const float* embed  = (const float*)d_in[1];
    const float* ff_w1  = (const float*)d_in[2];
    const float* ff_b1  = (const float*)d_in[3];
    const float* ff_w2  = (const float*)d_in[4];
    const float* ff_b2  = (const float*)d_in[5];
    const float* ln_g   = (const float*)d_in[6];
    const float* ln_b   = (const float*)d_in[7];
    const float* sem_w  = (const float*)d_in[8];
    const float* sem_b  = (const float*)d_in[9];
    const float* epi_w  = (const float*)d_in[10];
    const float* epi_b  = (const float*)d_in[11];
    const float* out_w  = (const float*)d_in[12];
    const float* out_b  = (const float*)d_in[13];
    float* outp = (float*)d_out;

    // workspace: 87.2 MB total (no encoder intermediates)
    char* w = (char*)d_ws;
    size_t off = 0;
    ushort_t* ks_bf = (ushort_t*)(w + off); off += 33554432;          // 65536x256 bf16
    ushort_t* ke_bf = (ushort_t*)(w + off); off += 33554432;
    ushort_t* w1t   = (ushort_t*)(w + off); off += 1048576;
    ushort_t* w2t   = (ushort_t*)(w + off); off += 1048576;
    ushort_t* semt  = (ushort_t*)(w + off); off += 262144;            // semt|epit adjacent
    ushort_t* epit  = (ushort_t*)(w + off); off += 262144;
    float*    bet_s = (float*)(w + off);    off += 262144;
    float*    bet_e = (float*)(w + off);    off += 262144;
    float*    cbuf  = (float*)(w + off);    off += 131072;
    ushort_t* Dbuf  = (ushort_t*)(w + off); off += 16777216;          // Tinv-I

    // weight prep (bf16 + transpose)
    transpose_cvt<<<dim3(1024 / 32, 512 / 32), 256, 0, stream>>>(ff_w1, w1t, 512, 1024);
    transpose_cvt<<<dim3(512 / 32, 1024 / 32), 256, 0, stream>>>(ff_w2, w2t, 1024, 512);
    transpose_cvt<<<dim3(256 / 32, 512 / 32), 256, 0, stream>>>(sem_w, semt, 512, 256);
    transpose_cvt<<<dim3(256 / 32, 512 / 32), 256, 0, stream>>>(epi_w, epit, 512, 256);

    // fully fused encoder: embed-gather + FFN + residual + LN + proj + beta
    enc_fused<<<1024, 512, 0, stream>>>(
        seq, embed, w1t, w2t, ff_b1, ff_b2, ln_g, ln_b,
        semt, sem_b, epi_b, ks_bf, ke_bf, bet_s, bet_e);

    tinv_kernel<<<512, 256, 0, stream>>>(ks_bf, ke_bf, bet_s, bet_e, Dbuf);
    scan_kernel<<<256, 512, 0, stream>>>(ks_bf, ke_bf, bet_s, bet_e, Dbuf, cbuf);

    out_gemm<<<dim3(125, 4), 512, 0, stream>>>(cbuf, out_w, out_b, outp);
}